// Round 11
// baseline (356.539 us; speedup 1.0000x reference)
//
#include <hip/hip_runtime.h>

// MultiHead attention, B=4 L=2048 D=1024 H=16 HD=64.
// R19: qkv_gemm single-barrier double-buffered prefetch (attn4's R12/R18
// structure, ported verbatim). R18 counters for qkv_gemm: MfmaUtil 22 +
// VALUBusy 23 = 45% combined issue, conflicts 0, HBM 34% -> majority of
// cycles are the serialized stage->drain->compute pattern exposing full
// load latency each of 16 K-steps. New: As/Bs[2][128][64] (64KB, 2 blk/CU
// like attn4), prologue stages step 0; per iter: barrier -> prefetch t+1
// into other buffer -> ds_read + 32 MFMA from current. Barriers 32->16,
// load latency hidden under compute. K order unchanged (steps ascending,
// kk outer) -> absmax must stay bit-identical 1.464844e-3.
// attn4 (R18: KVBLK=128), gemm_wo, casts, launcher unchanged.

#define Bsz 4
#define Lq 2048
#define Dm 1024
#define NH 16
#define HD 64
// 0.125 * log2(e): folded into Wq/bq so attention uses exp2 directly
#define QSCALE 0.18033688011112042f

typedef unsigned short u16;
typedef __attribute__((ext_vector_type(4))) short bf16x4;
typedef __attribute__((ext_vector_type(8))) short short8;
typedef __attribute__((ext_vector_type(4))) float f32x4;

#define MFMA32(a, b, c) __builtin_amdgcn_mfma_f32_16x16x32_bf16(a, b, c, 0, 0, 0)

typedef __attribute__((address_space(3))) unsigned su32;
typedef __attribute__((address_space(1))) unsigned gu32;
__device__ __forceinline__ void gl_lds16(const u16* g, u16* l) {
  __builtin_amdgcn_global_load_lds((gu32*)(g), (su32*)(l), 16, 0, 0);
}

__device__ __forceinline__ u16 f2b(float x) {
  unsigned u = __builtin_bit_cast(unsigned, x);
  return (u16)((u + 0x7fffu + ((u >> 16) & 1u)) >> 16);  // RNE
}
__device__ __forceinline__ unsigned pk2(float a, float b) {
  return (unsigned)f2b(a) | ((unsigned)f2b(b) << 16);
}
// round-half-up bf16 pair pack via v_perm: lo=bf16(a), hi=bf16(b)
__device__ __forceinline__ unsigned pk2p(float a, float b) {
  return __builtin_amdgcn_perm(__builtin_bit_cast(unsigned, b) + 0x8000u,
                               __builtin_bit_cast(unsigned, a) + 0x8000u, 0x07060302u);
}
// packed bf16 pair, RTZ (single VALU op) — P-weights only, never outputs
__device__ __forceinline__ unsigned cvtpk(float a, float b) {
  unsigned r;
  asm("v_cvt_pk_bf16_f32 %0, %1, %2" : "=v"(r) : "v"(a), "v"(b));
  return r;
}
__device__ __forceinline__ float fexp2(float x) {
#if __has_builtin(__builtin_amdgcn_exp2f)
  return __builtin_amdgcn_exp2f(x);
#else
  return exp2f(x);
#endif
}

// ---------------- fused triple activation cast fp32 -> bf16 ----------------
__global__ void castk3(const float* __restrict__ q, const float* __restrict__ k,
                       const float* __restrict__ v, u16* __restrict__ dst) {
  const float* s = blockIdx.y == 0 ? q : (blockIdx.y == 1 ? k : v);
  u16* d = dst + (size_t)blockIdx.y * (Bsz * Lq * Dm);
  int i = (blockIdx.x * 256 + threadIdx.x) * 8;
  float4 a = *(const float4*)(s + i);
  float4 b = *(const float4*)(s + i + 4);
  short8 o;
  o[0] = (short)f2b(a.x); o[1] = (short)f2b(a.y);
  o[2] = (short)f2b(a.z); o[3] = (short)f2b(a.w);
  o[4] = (short)f2b(b.x); o[5] = (short)f2b(b.y);
  o[6] = (short)f2b(b.z); o[7] = (short)f2b(b.w);
  *(short8*)(d + i) = o;
}

// fused 4-weight cast, blockIdx.y selects matrix
__global__ void castw(const float* __restrict__ s0, const float* __restrict__ s1,
                      const float* __restrict__ s2, const float* __restrict__ s3,
                      u16* __restrict__ d0, u16* __restrict__ d1,
                      u16* __restrict__ d2, u16* __restrict__ d3) {
  const float* s; u16* d; float sc = 1.0f;
  switch (blockIdx.y) {
    case 0: s = s0; d = d0; sc = QSCALE; break;
    case 1: s = s1; d = d1; break;
    case 2: s = s2; d = d2; break;
    default: s = s3; d = d3; break;
  }
  int i = (blockIdx.x * 256 + threadIdx.x) * 8;
  float4 a = *(const float4*)(s + i);
  float4 b = *(const float4*)(s + i + 4);
  short8 o;
  o[0] = (short)f2b(a.x * sc); o[1] = (short)f2b(a.y * sc);
  o[2] = (short)f2b(a.z * sc); o[3] = (short)f2b(a.w * sc);
  o[4] = (short)f2b(b.x * sc); o[5] = (short)f2b(b.y * sc);
  o[6] = (short)f2b(b.z * sc); o[7] = (short)f2b(b.w * sc);
  *(short8*)(d + i) = o;
}

// ---------------- fused QKV projection GEMM ----------------
// grid (8, 64, 3). z: {q->Qh (scaled), k->Kh, v->Vtg (transposed+permuted)}.
// BK=64, XOR-swizzled LDS, 2-deep double buffer, ONE barrier per K-step.
__global__ __launch_bounds__(256) void qkv_gemm(
    const u16* __restrict__ Ab,
    const u16* __restrict__ Wqb, const u16* __restrict__ Wkb, const u16* __restrict__ Wvb,
    const float* __restrict__ bq, const float* __restrict__ bk, const float* __restrict__ bv,
    u16* __restrict__ Qh, u16* __restrict__ Kh, u16* __restrict__ Vtg)
{
  __shared__ __align__(16) u16 As[2][128 * 64];   // [buf][row*64], chunk-swizzled
  __shared__ __align__(16) u16 Bs[2][128 * 64];
  const int z = blockIdx.z;
  const u16* A  = Ab + (size_t)z * (Bsz * Lq * Dm);
  const u16* Bt = z == 0 ? Wqb : (z == 1 ? Wkb : Wvb);
  const float* bias = z == 0 ? bq : (z == 1 ? bk : bv);
  const float bscale = z == 0 ? QSCALE : 1.0f;

  const int tid  = threadIdx.x;
  const int lane = tid & 63;
  const int wave = tid >> 6;
  const int quad = lane >> 4;
  const int r16  = lane & 15;
  const int wm   = (wave >> 1) * 64;
  const int wn   = (wave & 1) * 64;
  const int m0   = blockIdx.y * 128;
  const int n0   = blockIdx.x * 128;

  // Staging: wave stages rows [wave*32, wave*32+32) in 4 gl_lds of 8 rows.
  // Instr i, lane l -> LDS elem wave*2048 + i*512 + l*8; phys chunk l&7,
  // row&7 = l>>3 -> source logical chunk = (l&7)^(l>>3).
  const int srcc = ((lane & 7) ^ (lane >> 3)) * 8;   // source chunk offset, elems
  const int r0   = wave * 32 + (lane >> 3);          // tile row for instr 0
  const u16* ga = A  + (size_t)(m0 + r0) * Dm + srcc;
  const u16* gb = Bt + (size_t)(n0 + r0) * Dm + srcc;
  u16* lab = &As[0][0];
  u16* lbb = &Bs[0][0];
  const int ldst = wave * 2048;   // wave-uniform LDS base within a buffer

  // prologue: stage K-step 0 into buffer 0
#pragma unroll
  for (int i = 0; i < 4; ++i) {
    gl_lds16(ga + (size_t)(8 * i) * Dm, lab + ldst + i * 512);
    gl_lds16(gb + (size_t)(8 * i) * Dm, lbb + ldst + i * 512);
  }

  f32x4 acc[4][4] = {};
  const int sx = r16 & 7;   // read-side swizzle key (read rows are 16k+r16)

  for (int t = 0; t < 16; ++t) {
    // top barrier: vmcnt(0) drains this wave's step-t loads; barrier gives
    // cross-wave visibility AND write-after-read safety for the other buffer.
    __syncthreads();
    const int cur = (t & 1) * 8192;
    const int nxt = 8192 - cur;
    if (t < 15) {
      const size_t ko = (size_t)(t + 1) * 64;
#pragma unroll
      for (int i = 0; i < 4; ++i) {
        gl_lds16(ga + ko + (size_t)(8 * i) * Dm, lab + nxt + ldst + i * 512);
        gl_lds16(gb + ko + (size_t)(8 * i) * Dm, lbb + nxt + ldst + i * 512);
      }
    }

    short8 af[4][2], bfr[4][2];
#pragma unroll
    for (int mt = 0; mt < 4; ++mt)
#pragma unroll
      for (int kk = 0; kk < 2; ++kk)
        af[mt][kk] = *(const short8*)(lab + cur + (wm + mt * 16 + r16) * 64 + ((kk * 4 + quad) ^ sx) * 8);
#pragma unroll
    for (int nt = 0; nt < 4; ++nt)
#pragma unroll
      for (int kk = 0; kk < 2; ++kk)
        bfr[nt][kk] = *(const short8*)(lbb + cur + (wn + nt * 16 + r16) * 64 + ((kk * 4 + quad) ^ sx) * 8);
    // kk outer so each acc sees k in increasing order (bit-identical)
#pragma unroll
    for (int kk = 0; kk < 2; ++kk)
#pragma unroll
      for (int mt = 0; mt < 4; ++mt)
#pragma unroll
        for (int nt = 0; nt < 4; ++nt)
          acc[mt][nt] = MFMA32(af[mt][kk], bfr[nt][kk], acc[mt][nt]);
  }

#pragma unroll
  for (int mt = 0; mt < 4; ++mt) {
#pragma unroll
    for (int nt = 0; nt < 4; ++nt) {
      int n = n0 + wn + nt * 16 + r16;
      float bv_ = bias[n] * bscale;
      if (z == 2) {
        // V: transposed head-split Vtg[bh][d][l'], column-permuted within each
        // 32-block: l' = (l&~31) | q<<3 | w<<2 | j  (q=(l>>2)&3, w=(l>>4)&1)
        // so attention's b128 A-frag slot (quad,i=4w+j) carries the kpos that
        // the P B-frag holds in the same slot.
        int m_base = m0 + wm + mt * 16 + quad * 4;
        int b = m_base >> 11, l0 = m_base & 2047;
        int lp = (l0 & ~31) | (((l0 >> 2) & 3) << 3) | (((l0 >> 4) & 1) << 2);
        int h = n >> 6, d = n & 63;
        u16* dst = Vtg + (((size_t)(b * NH + h)) * HD + d) * Lq + lp;
        uint2 pkd;
        pkd.x = pk2(acc[mt][nt][0] + bv_, acc[mt][nt][1] + bv_);
        pkd.y = pk2(acc[mt][nt][2] + bv_, acc[mt][nt][3] + bv_);
        *(uint2*)dst = pkd;
      } else {
        u16* dst = z == 0 ? Qh : Kh;
#pragma unroll
        for (int j = 0; j < 4; ++j) {
          int m = m0 + wm + mt * 16 + quad * 4 + j;
          int b = m >> 11, l = m & 2047;
          int h = n >> 6,  d = n & 63;
          dst[(((size_t)(b * NH + h)) * Lq + l) * HD + d] = f2b(acc[mt][nt][j] + bv_);
        }
      }
    }
  }
}

// ---------------- Wo GEMM: 128x64 tile, fp32 out ----------------
__global__ __launch_bounds__(256) void gemm_wo(
    const u16* __restrict__ A, const u16* __restrict__ Bt,
    const float* __restrict__ bias, float* __restrict__ C)
{
  __shared__ __align__(16) u16 As[128 * 32];
  __shared__ __align__(16) u16 Bs[64 * 32];
  const int tid  = threadIdx.x;
  const int lane = tid & 63;
  const int wave = tid >> 6;
  const int quad = lane >> 4;
  const int r16  = lane & 15;
  const int wm   = wave * 32;
  const int m0   = blockIdx.y * 128;
  const int n0   = blockIdx.x * 64;

  const u16* ga = A  + (size_t)(m0 + wave * 32 + (lane >> 2)) * Dm + (lane & 3) * 8;
  const u16* gb = Bt + (size_t)(n0 + wave * 16 + (lane >> 2)) * Dm + (lane & 3) * 8;
  u16* la = As + wave * 1024;
  u16* lb = Bs + wave * 512;

  f32x4 acc[2][4] = {};

  for (int k0 = 0; k0 < Dm; k0 += 32) {
    gl_lds16(ga + k0, la);
    gl_lds16(ga + k0 + 16 * Dm, la + 512);
    gl_lds16(gb + k0, lb);
    __syncthreads();

    short8 af[2], bfr[4];
#pragma unroll
    for (int mt = 0; mt < 2; ++mt) af[mt]  = *(const short8*)&As[(wm + mt * 16 + r16) * 32 + quad * 8];
#pragma unroll
    for (int nt = 0; nt < 4; ++nt) bfr[nt] = *(const short8*)&Bs[(nt * 16 + r16) * 32 + quad * 8];
#pragma unroll
    for (int mt = 0; mt < 2; ++mt)
#pragma unroll
      for (int nt = 0; nt < 4; ++nt)
        acc[mt][nt] = MFMA32(af[mt], bfr[nt], acc[mt][nt]);
    __syncthreads();
  }

#pragma unroll
  for (int mt = 0; mt < 2; ++mt) {
#pragma unroll
    for (int nt = 0; nt < 4; ++nt) {
      int n = n0 + nt * 16 + r16;
      float bv = bias[n];
#pragma unroll
      for (int j = 0; j < 4; ++j) {
        int m = m0 + wm + mt * 16 + quad * 4 + j;
        C[(size_t)m * Dm + n] = acc[mt][nt][j] + bv;
      }
    }
  }
}

// ---------------- fused flash attention (S^T form, K=32 PV) ----------------
// Qh (pre-scaled), Kh: [bh][L][HD] bf16. Vtg: [bh][HD][L] bf16, col-permuted.
// Oa: [B*L][D] bf16 row-major. Block: 4 waves x 64 q = 256 q; k-tiles of 128.
// LDS 2-deep double buffer (64KB), XOR-swizzled, filled by global_load_lds
// with pre-swizzled global sources.
__global__ __launch_bounds__(256) void attn4(
    const u16* __restrict__ Qh, const u16* __restrict__ Kh,
    const u16* __restrict__ Vtg, u16* __restrict__ Oa)
{
  const int bh = blockIdx.y;   // 0..63
  const int qt = blockIdx.x;   // 0..7
  const int tid = threadIdx.x, lane = tid & 63, wave = tid >> 6;
  const int quad = lane >> 4, r16 = lane & 15;

  __shared__ __align__(16) u16 Ks[2][128][64];   // [buf][kpos][d], chunk-swizzled
  __shared__ __align__(16) u16 Vt[2][64][128];   // [buf][d][kpos'] (permuted), chunk-swizzled

  const int qbase = qt * 256 + wave * 64;
  short8 aq[4][2];
#pragma unroll
  for (int qf = 0; qf < 4; ++qf) {
    const size_t qrow = ((size_t)bh * Lq + qbase + qf * 16 + r16) * HD;
    aq[qf][0] = *(const short8*)(Qh + qrow + quad * 8);
    aq[qf][1] = *(const short8*)(Qh + qrow + 32 + quad * 8);
  }

  const short8 ones8 = {0x3F80, 0x3F80, 0x3F80, 0x3F80, 0x3F80, 0x3F80, 0x3F80, 0x3F80};

  f32x4 oacc[4][4] = {};
  f32x4 lacc[4] = {};   // ones*P: every row = column sum of P; col = r16 = own q

  // --- K staging (rows 128, 64 elems = 8 chunks/row) ---
  // Wave stages rows [wave*32, +32) in 4 instrs of 8 rows: instr i, lane l ->
  // LDS elem wave*2048 + i*512 + l*8; row = wave*32 + 8i + (l>>3), phys chunk
  // l&7, key = row&7 = l>>3 (i-invariant) -> source chunk (l&7)^(l>>3).
  const int ksrc = ((lane & 7) ^ (lane >> 3)) * 8;
  const u16* kg0 = Kh + ((size_t)bh * Lq + wave * 32 + (lane >> 3)) * HD + ksrc;
  // --- V staging (rows 64, 128 elems = 16 chunks/row) ---
  // Wave stages rows [wave*16, +16) in 4 instrs of 4 rows: instr i, lane l ->
  // LDS elem wave*2048 + i*512 + l*8; row = wave*16 + 4i + (l>>4), phys chunk
  // l&15, key = row&7 = (4i+(l>>4))&7 = (l>>4)|((i&1)<<2) -> source chunk
  // (l&15)^key, i-dependent: fold into 4 per-instr pointers.
  const u16* vgp[4];
#pragma unroll
  for (int i = 0; i < 4; ++i) {
    int vrow = wave * 16 + 4 * i + (lane >> 4);
    int vkey = (lane >> 4) | ((i & 1) << 2);
    int vsc  = ((lane & 15) ^ vkey) * 8;
    vgp[i] = Vtg + ((size_t)bh * HD + vrow) * Lq + vsc;
  }
  u16* ksb = &Ks[0][0][0];
  u16* vtb = &Vt[0][0][0];
  const int ldst = wave * 2048;   // wave-uniform LDS base within a buffer, elems

  // prologue: stage tile 0 into buffer 0
#pragma unroll
  for (int i = 0; i < 4; ++i) {
    gl_lds16(kg0 + (size_t)(8 * i) * HD, ksb + ldst + i * 512);
    gl_lds16(vgp[i],                     vtb + ldst + i * 512);
  }

  const int sx = r16 & 7;           // read-side swizzle key (rows are 16k+r16)

  for (int t = 0; t < 16; ++t) {
    // barrier: compiler emits s_waitcnt vmcnt(0) before s_barrier, draining
    // this wave's tile-t loads; barrier gives cross-wave visibility.
    __syncthreads();
    const int cur = (t & 1) * 8192;
    const int nxt = 8192 - cur;
    if (t < 15) {
      const size_t ko = (size_t)(t + 1) * (128 * HD);
      const int    vo = (t + 1) * 128;
#pragma unroll
      for (int i = 0; i < 4; ++i) {
        gl_lds16(kg0 + ko + (size_t)(8 * i) * HD, ksb + nxt + ldst + i * 512);
        gl_lds16(vgp[i] + vo,                     vtb + nxt + ldst + i * 512);
      }
    }

#pragma unroll
    for (int w = 0; w < 4; ++w) {
      // K fragments for the two 16-kpos chunks of this 32-window (shared
      // across all 4 q fragments)
      short8 kf[2][2];
#pragma unroll
      for (int mtl = 0; mtl < 2; ++mtl) {
        const int mt = 2 * w + mtl;
        kf[mtl][0] = *(const short8*)(ksb + cur + (mt * 16 + r16) * 64 + ((quad    ) ^ sx) * 8);
        kf[mtl][1] = *(const short8*)(ksb + cur + (mt * 16 + r16) * 64 + ((quad + 4) ^ sx) * 8);
      }
      // V A-frags for this window (permuted layout -> direct b128), shared
      // across all 4 q fragments
      short8 vf[4];
#pragma unroll
      for (int nt = 0; nt < 4; ++nt)
        vf[nt] = *(const short8*)(vtb + cur + (nt * 16 + r16) * 128 + ((w * 4 + quad) ^ sx) * 8);
      // per-qf: S^T, softmax, PV at K=32 (4 independent chains for ILP).
      // P packed RTZ; lsum MFMA-summed from the SAME truncated P, so the
      // RTZ bias cancels exactly in the final O = num/den ratio.
#pragma unroll
      for (int qf = 0; qf < 4; ++qf) {
        f32x4 sa = {}, sb = {};
        sa = MFMA32(kf[0][0], aq[qf][0], sa);
        sa = MFMA32(kf[0][1], aq[qf][1], sa);
        sb = MFMA32(kf[1][0], aq[qf][0], sb);
        sb = MFMA32(kf[1][1], aq[qf][1], sb);
        uint4 pu;
        pu.x = cvtpk(fexp2(sa[0]), fexp2(sa[1]));
        pu.y = cvtpk(fexp2(sa[2]), fexp2(sa[3]));
        pu.z = cvtpk(fexp2(sb[0]), fexp2(sb[1]));
        pu.w = cvtpk(fexp2(sb[2]), fexp2(sb[3]));
        short8 pb = __builtin_bit_cast(short8, pu);
        lacc[qf] = MFMA32(ones8, pb, lacc[qf]);
#pragma unroll
        for (int nt = 0; nt < 4; ++nt)
          oacc[qf][nt] = MFMA32(vf[nt], pb, oacc[qf][nt]);
      }
    }
  }

  const int b = bh >> 4, h = bh & 15;
  // lacc: ones*P rows all equal the P column-sum; col = r16 = this lane's q
  // in the epilogue mapping below -> no cross-lane reduction needed.
  float linv[4];
#pragma unroll
  for (int qf = 0; qf < 4; ++qf) linv[qf] = 1.0f / lacc[qf][0];
#pragma unroll
  for (int qf = 0; qf < 4; ++qf) {
    int q = qbase + qf * 16 + r16;
    size_t rowb = ((size_t)(b * Lq + q)) * Dm + h * HD;
#pragma unroll
    for (int nt = 0; nt < 4; ++nt) {
      f32x4 o = oacc[qf][nt];
      uint2 pkd;
      pkd.x = pk2(o[0] * linv[qf], o[1] * linv[qf]);
      pkd.y = pk2(o[2] * linv[qf], o[3] * linv[qf]);
      *(uint2*)&Oa[rowb + nt * 16 + quad * 4] = pkd;
    }
  }
}

// ---------------- launcher ----------------
extern "C" void kernel_launch(void* const* d_in, const int* in_sizes, int n_in,
                              void* d_out, int out_size, void* d_ws, size_t ws_size,
                              hipStream_t stream) {
  const float* q  = (const float*)d_in[0];
  const float* k  = (const float*)d_in[1];
  const float* v  = (const float*)d_in[2];
  const float* Wq = (const float*)d_in[3];
  const float* bq = (const float*)d_in[4];
  const float* Wk = (const float*)d_in[5];
  const float* bk = (const float*)d_in[6];
  const float* Wv = (const float*)d_in[7];
  const float* bv = (const float*)d_in[8];
  const float* Wo = (const float*)d_in[9];
  const float* bo = (const float*)d_in[10];

  const int NA = Bsz * Lq * Dm;  // 8388608
  u16* abuf = (u16*)d_ws;            // [3][M][K] activations bf16; later Oa
  u16* Qh   = abuf + (size_t)3 * NA;
  u16* Kh   = Qh   + NA;
  u16* Vtg  = Kh   + NA;
  u16* wqb  = Vtg  + NA;
  u16* wkb  = wqb  + 1048576;
  u16* wvb  = wkb  + 1048576;
  u16* wob  = wvb  + 1048576;

  castw<<<dim3(512, 4), 256, 0, stream>>>(Wq, Wk, Wv, Wo, wqb, wkb, wvb, wob);
  castk3<<<dim3(NA / 2048, 3), 256, 0, stream>>>(q, k, v, abuf);

  qkv_gemm<<<dim3(8, 64, 3), 256, 0, stream>>>(abuf, wqb, wkb, wvb, bq, bk, bv, Qh, Kh, Vtg);

  attn4<<<dim3(Lq / 256, Bsz * NH), 256, 0, stream>>>(Qh, Kh, Vtg, abuf);

  gemm_wo<<<dim3(16, 64), 256, 0, stream>>>(abuf, wob, bo, (float*)d_out);
}

// Round 13
// 336.583 us; speedup vs baseline: 1.0593x; 1.0593x over previous
//
#include <hip/hip_runtime.h>

// MultiHead attention, B=4 L=2048 D=1024 H=16 HD=64.
// R21 == R20 resubmitted (R20 bench was a broker infra failure, no kernel
// signal; R14/R15 showed the same error resolving on identical resubmit).
// (a) qkv_gemm reverted to R17/R18 structure (BK=64+swizzle, 2 barriers,
// 32KB) — R19's single-barrier dbuf was neutral on time (95->97us), cost 2x
// LDS and +7pts VALUBusy: load latency was NOT the exposed cost. (b) gemm_wo
// ported to the same proven structure (was BK=32, unswizzled = the 8-way
// conflict + 64-barrier disease qkv had pre-R17). A staging identical to
// qkv; B (64 rows): wave stages 16 rows in 2 instrs of 8 rows, same key
// l>>3, source chunk (l&7)^(l>>3). kk-outer keeps k ascending -> absmax
// must stay bit-identical 1.464844e-3.
// attn4 (R18: KVBLK=128, ones-MFMA lsum, RTZ P-pack), casts unchanged.

#define Bsz 4
#define Lq 2048
#define Dm 1024
#define NH 16
#define HD 64
// 0.125 * log2(e): folded into Wq/bq so attention uses exp2 directly
#define QSCALE 0.18033688011112042f

typedef unsigned short u16;
typedef __attribute__((ext_vector_type(4))) short bf16x4;
typedef __attribute__((ext_vector_type(8))) short short8;
typedef __attribute__((ext_vector_type(4))) float f32x4;

#define MFMA32(a, b, c) __builtin_amdgcn_mfma_f32_16x16x32_bf16(a, b, c, 0, 0, 0)

typedef __attribute__((address_space(3))) unsigned su32;
typedef __attribute__((address_space(1))) unsigned gu32;
__device__ __forceinline__ void gl_lds16(const u16* g, u16* l) {
  __builtin_amdgcn_global_load_lds((gu32*)(g), (su32*)(l), 16, 0, 0);
}

__device__ __forceinline__ u16 f2b(float x) {
  unsigned u = __builtin_bit_cast(unsigned, x);
  return (u16)((u + 0x7fffu + ((u >> 16) & 1u)) >> 16);  // RNE
}
__device__ __forceinline__ unsigned pk2(float a, float b) {
  return (unsigned)f2b(a) | ((unsigned)f2b(b) << 16);
}
// round-half-up bf16 pair pack via v_perm: lo=bf16(a), hi=bf16(b)
__device__ __forceinline__ unsigned pk2p(float a, float b) {
  return __builtin_amdgcn_perm(__builtin_bit_cast(unsigned, b) + 0x8000u,
                               __builtin_bit_cast(unsigned, a) + 0x8000u, 0x07060302u);
}
// packed bf16 pair, RTZ (single VALU op) — P-weights only, never outputs
__device__ __forceinline__ unsigned cvtpk(float a, float b) {
  unsigned r;
  asm("v_cvt_pk_bf16_f32 %0, %1, %2" : "=v"(r) : "v"(a), "v"(b));
  return r;
}
__device__ __forceinline__ float fexp2(float x) {
#if __has_builtin(__builtin_amdgcn_exp2f)
  return __builtin_amdgcn_exp2f(x);
#else
  return exp2f(x);
#endif
}

// ---------------- fused triple activation cast fp32 -> bf16 ----------------
__global__ void castk3(const float* __restrict__ q, const float* __restrict__ k,
                       const float* __restrict__ v, u16* __restrict__ dst) {
  const float* s = blockIdx.y == 0 ? q : (blockIdx.y == 1 ? k : v);
  u16* d = dst + (size_t)blockIdx.y * (Bsz * Lq * Dm);
  int i = (blockIdx.x * 256 + threadIdx.x) * 8;
  float4 a = *(const float4*)(s + i);
  float4 b = *(const float4*)(s + i + 4);
  short8 o;
  o[0] = (short)f2b(a.x); o[1] = (short)f2b(a.y);
  o[2] = (short)f2b(a.z); o[3] = (short)f2b(a.w);
  o[4] = (short)f2b(b.x); o[5] = (short)f2b(b.y);
  o[6] = (short)f2b(b.z); o[7] = (short)f2b(b.w);
  *(short8*)(d + i) = o;
}

// fused 4-weight cast, blockIdx.y selects matrix
__global__ void castw(const float* __restrict__ s0, const float* __restrict__ s1,
                      const float* __restrict__ s2, const float* __restrict__ s3,
                      u16* __restrict__ d0, u16* __restrict__ d1,
                      u16* __restrict__ d2, u16* __restrict__ d3) {
  const float* s; u16* d; float sc = 1.0f;
  switch (blockIdx.y) {
    case 0: s = s0; d = d0; sc = QSCALE; break;
    case 1: s = s1; d = d1; break;
    case 2: s = s2; d = d2; break;
    default: s = s3; d = d3; break;
  }
  int i = (blockIdx.x * 256 + threadIdx.x) * 8;
  float4 a = *(const float4*)(s + i);
  float4 b = *(const float4*)(s + i + 4);
  short8 o;
  o[0] = (short)f2b(a.x * sc); o[1] = (short)f2b(a.y * sc);
  o[2] = (short)f2b(a.z * sc); o[3] = (short)f2b(a.w * sc);
  o[4] = (short)f2b(b.x * sc); o[5] = (short)f2b(b.y * sc);
  o[6] = (short)f2b(b.z * sc); o[7] = (short)f2b(b.w * sc);
  *(short8*)(d + i) = o;
}

// ---------------- fused QKV projection GEMM ----------------
// grid (8, 64, 3). z: {q->Qh (scaled), k->Kh, v->Vtg (transposed+permuted)}.
// BK=64, XOR-swizzled LDS, 2 barriers per K-step, 16 steps. (R17 structure.)
__global__ __launch_bounds__(256) void qkv_gemm(
    const u16* __restrict__ Ab,
    const u16* __restrict__ Wqb, const u16* __restrict__ Wkb, const u16* __restrict__ Wvb,
    const float* __restrict__ bq, const float* __restrict__ bk, const float* __restrict__ bv,
    u16* __restrict__ Qh, u16* __restrict__ Kh, u16* __restrict__ Vtg)
{
  __shared__ __align__(16) u16 As[128 * 64];   // [row][64], chunk-swizzled
  __shared__ __align__(16) u16 Bs[128 * 64];
  const int z = blockIdx.z;
  const u16* A  = Ab + (size_t)z * (Bsz * Lq * Dm);
  const u16* Bt = z == 0 ? Wqb : (z == 1 ? Wkb : Wvb);
  const float* bias = z == 0 ? bq : (z == 1 ? bk : bv);
  const float bscale = z == 0 ? QSCALE : 1.0f;

  const int tid  = threadIdx.x;
  const int lane = tid & 63;
  const int wave = tid >> 6;
  const int quad = lane >> 4;
  const int r16  = lane & 15;
  const int wm   = (wave >> 1) * 64;
  const int wn   = (wave & 1) * 64;
  const int m0   = blockIdx.y * 128;
  const int n0   = blockIdx.x * 128;

  // Staging: wave stages rows [wave*32, wave*32+32) in 4 gl_lds of 8 rows.
  // Instr i, lane l -> LDS elem wave*2048 + i*512 + l*8; phys chunk l&7,
  // row&7 = l>>3 -> source logical chunk = (l&7)^(l>>3).
  const int srcc = ((lane & 7) ^ (lane >> 3)) * 8;   // source chunk offset, elems
  const int r0   = wave * 32 + (lane >> 3);          // tile row for instr 0
  const u16* ga = A  + (size_t)(m0 + r0) * Dm + srcc;
  const u16* gb = Bt + (size_t)(n0 + r0) * Dm + srcc;
  u16* la = As + wave * 2048;
  u16* lb = Bs + wave * 2048;

  f32x4 acc[4][4] = {};
  const int sx = r16 & 7;   // read-side swizzle key (read rows are 16k+r16)

  for (int k0 = 0; k0 < Dm; k0 += 64) {
#pragma unroll
    for (int i = 0; i < 4; ++i) {
      gl_lds16(ga + k0 + (size_t)(8 * i) * Dm, la + i * 512);
      gl_lds16(gb + k0 + (size_t)(8 * i) * Dm, lb + i * 512);
    }
    __syncthreads();

    short8 af[4][2], bfr[4][2];
#pragma unroll
    for (int mt = 0; mt < 4; ++mt)
#pragma unroll
      for (int kk = 0; kk < 2; ++kk)
        af[mt][kk] = *(const short8*)&As[(wm + mt * 16 + r16) * 64 + ((kk * 4 + quad) ^ sx) * 8];
#pragma unroll
    for (int nt = 0; nt < 4; ++nt)
#pragma unroll
      for (int kk = 0; kk < 2; ++kk)
        bfr[nt][kk] = *(const short8*)&Bs[(wn + nt * 16 + r16) * 64 + ((kk * 4 + quad) ^ sx) * 8];
    // kk outer so each acc sees k in increasing order (bit-identical to BK=32)
#pragma unroll
    for (int kk = 0; kk < 2; ++kk)
#pragma unroll
      for (int mt = 0; mt < 4; ++mt)
#pragma unroll
        for (int nt = 0; nt < 4; ++nt)
          acc[mt][nt] = MFMA32(af[mt][kk], bfr[nt][kk], acc[mt][nt]);
    __syncthreads();
  }

#pragma unroll
  for (int mt = 0; mt < 4; ++mt) {
#pragma unroll
    for (int nt = 0; nt < 4; ++nt) {
      int n = n0 + wn + nt * 16 + r16;
      float bv_ = bias[n] * bscale;
      if (z == 2) {
        // V: transposed head-split Vtg[bh][d][l'], column-permuted within each
        // 32-block: l' = (l&~31) | q<<3 | w<<2 | j  (q=(l>>2)&3, w=(l>>4)&1)
        // so attention's b128 A-frag slot (quad,i=4w+j) carries the kpos that
        // the P B-frag holds in the same slot.
        int m_base = m0 + wm + mt * 16 + quad * 4;
        int b = m_base >> 11, l0 = m_base & 2047;
        int lp = (l0 & ~31) | (((l0 >> 2) & 3) << 3) | (((l0 >> 4) & 1) << 2);
        int h = n >> 6, d = n & 63;
        u16* dst = Vtg + (((size_t)(b * NH + h)) * HD + d) * Lq + lp;
        uint2 pkd;
        pkd.x = pk2(acc[mt][nt][0] + bv_, acc[mt][nt][1] + bv_);
        pkd.y = pk2(acc[mt][nt][2] + bv_, acc[mt][nt][3] + bv_);
        *(uint2*)dst = pkd;
      } else {
        u16* dst = z == 0 ? Qh : Kh;
#pragma unroll
        for (int j = 0; j < 4; ++j) {
          int m = m0 + wm + mt * 16 + quad * 4 + j;
          int b = m >> 11, l = m & 2047;
          int h = n >> 6,  d = n & 63;
          dst[(((size_t)(b * NH + h)) * Lq + l) * HD + d] = f2b(acc[mt][nt][j] + bv_);
        }
      }
    }
  }
}

// ---------------- Wo GEMM: 128x64 tile, BK=64, swizzled, fp32 out ----------------
__global__ __launch_bounds__(256) void gemm_wo(
    const u16* __restrict__ A, const u16* __restrict__ Bt,
    const float* __restrict__ bias, float* __restrict__ C)
{
  __shared__ __align__(16) u16 As[128 * 64];   // chunk-swizzled
  __shared__ __align__(16) u16 Bs[64 * 64];
  const int tid  = threadIdx.x;
  const int lane = tid & 63;
  const int wave = tid >> 6;
  const int quad = lane >> 4;
  const int r16  = lane & 15;
  const int wm   = wave * 32;
  const int m0   = blockIdx.y * 128;
  const int n0   = blockIdx.x * 64;

  // A staging: identical to qkv (32 rows/wave, 4 instrs of 8 rows).
  // B staging: 64 rows total, wave stages 16 rows in 2 instrs of 8 rows:
  // instr i, lane l -> LDS elem wave*1024 + i*512 + l*8; row = wave*16 +
  // 8i + (l>>3), phys chunk l&7, key = row&7 = l>>3 -> same srcc as A.
  const int srcc = ((lane & 7) ^ (lane >> 3)) * 8;
  const u16* ga = A  + (size_t)(m0 + wave * 32 + (lane >> 3)) * Dm + srcc;
  const u16* gb = Bt + (size_t)(n0 + wave * 16 + (lane >> 3)) * Dm + srcc;
  u16* la = As + wave * 2048;
  u16* lb = Bs + wave * 1024;

  f32x4 acc[2][4] = {};
  const int sx = r16 & 7;   // read rows are 16k+r16

  for (int k0 = 0; k0 < Dm; k0 += 64) {
#pragma unroll
    for (int i = 0; i < 4; ++i)
      gl_lds16(ga + k0 + (size_t)(8 * i) * Dm, la + i * 512);
#pragma unroll
    for (int i = 0; i < 2; ++i)
      gl_lds16(gb + k0 + (size_t)(8 * i) * Dm, lb + i * 512);
    __syncthreads();

    short8 af[2][2], bfr[4][2];
#pragma unroll
    for (int mt = 0; mt < 2; ++mt)
#pragma unroll
      for (int kk = 0; kk < 2; ++kk)
        af[mt][kk] = *(const short8*)&As[(wm + mt * 16 + r16) * 64 + ((kk * 4 + quad) ^ sx) * 8];
#pragma unroll
    for (int nt = 0; nt < 4; ++nt)
#pragma unroll
      for (int kk = 0; kk < 2; ++kk)
        bfr[nt][kk] = *(const short8*)&Bs[(nt * 16 + r16) * 64 + ((kk * 4 + quad) ^ sx) * 8];
    // kk outer keeps k ascending per acc (bit-identical to BK=32)
#pragma unroll
    for (int kk = 0; kk < 2; ++kk)
#pragma unroll
      for (int mt = 0; mt < 2; ++mt)
#pragma unroll
        for (int nt = 0; nt < 4; ++nt)
          acc[mt][nt] = MFMA32(af[mt][kk], bfr[nt][kk], acc[mt][nt]);
    __syncthreads();
  }

#pragma unroll
  for (int mt = 0; mt < 2; ++mt) {
#pragma unroll
    for (int nt = 0; nt < 4; ++nt) {
      int n = n0 + nt * 16 + r16;
      float bv = bias[n];
#pragma unroll
      for (int j = 0; j < 4; ++j) {
        int m = m0 + wm + mt * 16 + quad * 4 + j;
        C[(size_t)m * Dm + n] = acc[mt][nt][j] + bv;
      }
    }
  }
}

// ---------------- fused flash attention (S^T form, K=32 PV) ----------------
// Qh (pre-scaled), Kh: [bh][L][HD] bf16. Vtg: [bh][HD][L] bf16, col-permuted.
// Oa: [B*L][D] bf16 row-major. Block: 4 waves x 64 q = 256 q; k-tiles of 128.
// LDS 2-deep double buffer (64KB), XOR-swizzled, filled by global_load_lds
// with pre-swizzled global sources.
__global__ __launch_bounds__(256) void attn4(
    const u16* __restrict__ Qh, const u16* __restrict__ Kh,
    const u16* __restrict__ Vtg, u16* __restrict__ Oa)
{
  const int bh = blockIdx.y;   // 0..63
  const int qt = blockIdx.x;   // 0..7
  const int tid = threadIdx.x, lane = tid & 63, wave = tid >> 6;
  const int quad = lane >> 4, r16 = lane & 15;

  __shared__ __align__(16) u16 Ks[2][128][64];   // [buf][kpos][d], chunk-swizzled
  __shared__ __align__(16) u16 Vt[2][64][128];   // [buf][d][kpos'] (permuted), chunk-swizzled

  const int qbase = qt * 256 + wave * 64;
  short8 aq[4][2];
#pragma unroll
  for (int qf = 0; qf < 4; ++qf) {
    const size_t qrow = ((size_t)bh * Lq + qbase + qf * 16 + r16) * HD;
    aq[qf][0] = *(const short8*)(Qh + qrow + quad * 8);
    aq[qf][1] = *(const short8*)(Qh + qrow + 32 + quad * 8);
  }

  const short8 ones8 = {0x3F80, 0x3F80, 0x3F80, 0x3F80, 0x3F80, 0x3F80, 0x3F80, 0x3F80};

  f32x4 oacc[4][4] = {};
  f32x4 lacc[4] = {};   // ones*P: every row = column sum of P; col = r16 = own q

  // --- K staging (rows 128, 64 elems = 8 chunks/row) ---
  // Wave stages rows [wave*32, +32) in 4 instrs of 8 rows: instr i, lane l ->
  // LDS elem wave*2048 + i*512 + l*8; row = wave*32 + 8i + (l>>3), phys chunk
  // l&7, key = row&7 = l>>3 (i-invariant) -> source chunk (l&7)^(l>>3).
  const int ksrc = ((lane & 7) ^ (lane >> 3)) * 8;
  const u16* kg0 = Kh + ((size_t)bh * Lq + wave * 32 + (lane >> 3)) * HD + ksrc;
  // --- V staging (rows 64, 128 elems = 16 chunks/row) ---
  // Wave stages rows [wave*16, +16) in 4 instrs of 4 rows: instr i, lane l ->
  // LDS elem wave*2048 + i*512 + l*8; row = wave*16 + 4i + (l>>4), phys chunk
  // l&15, key = row&7 = (4i+(l>>4))&7 = (l>>4)|((i&1)<<2) -> source chunk
  // (l&15)^key, i-dependent: fold into 4 per-instr pointers.
  const u16* vgp[4];
#pragma unroll
  for (int i = 0; i < 4; ++i) {
    int vrow = wave * 16 + 4 * i + (lane >> 4);
    int vkey = (lane >> 4) | ((i & 1) << 2);
    int vsc  = ((lane & 15) ^ vkey) * 8;
    vgp[i] = Vtg + ((size_t)bh * HD + vrow) * Lq + vsc;
  }
  u16* ksb = &Ks[0][0][0];
  u16* vtb = &Vt[0][0][0];
  const int ldst = wave * 2048;   // wave-uniform LDS base within a buffer, elems

  // prologue: stage tile 0 into buffer 0
#pragma unroll
  for (int i = 0; i < 4; ++i) {
    gl_lds16(kg0 + (size_t)(8 * i) * HD, ksb + ldst + i * 512);
    gl_lds16(vgp[i],                     vtb + ldst + i * 512);
  }

  const int sx = r16 & 7;           // read-side swizzle key (rows are 16k+r16)

  for (int t = 0; t < 16; ++t) {
    // barrier: compiler emits s_waitcnt vmcnt(0) before s_barrier, draining
    // this wave's tile-t loads; barrier gives cross-wave visibility.
    __syncthreads();
    const int cur = (t & 1) * 8192;
    const int nxt = 8192 - cur;
    if (t < 15) {
      const size_t ko = (size_t)(t + 1) * (128 * HD);
      const int    vo = (t + 1) * 128;
#pragma unroll
      for (int i = 0; i < 4; ++i) {
        gl_lds16(kg0 + ko + (size_t)(8 * i) * HD, ksb + nxt + ldst + i * 512);
        gl_lds16(vgp[i] + vo,                     vtb + nxt + ldst + i * 512);
      }
    }

#pragma unroll
    for (int w = 0; w < 4; ++w) {
      // K fragments for the two 16-kpos chunks of this 32-window (shared
      // across all 4 q fragments)
      short8 kf[2][2];
#pragma unroll
      for (int mtl = 0; mtl < 2; ++mtl) {
        const int mt = 2 * w + mtl;
        kf[mtl][0] = *(const short8*)(ksb + cur + (mt * 16 + r16) * 64 + ((quad    ) ^ sx) * 8);
        kf[mtl][1] = *(const short8*)(ksb + cur + (mt * 16 + r16) * 64 + ((quad + 4) ^ sx) * 8);
      }
      // V A-frags for this window (permuted layout -> direct b128), shared
      // across all 4 q fragments
      short8 vf[4];
#pragma unroll
      for (int nt = 0; nt < 4; ++nt)
        vf[nt] = *(const short8*)(vtb + cur + (nt * 16 + r16) * 128 + ((w * 4 + quad) ^ sx) * 8);
      // per-qf: S^T, softmax, PV at K=32 (4 independent chains for ILP).
      // P packed RTZ; lsum MFMA-summed from the SAME truncated P, so the
      // RTZ bias cancels exactly in the final O = num/den ratio.
#pragma unroll
      for (int qf = 0; qf < 4; ++qf) {
        f32x4 sa = {}, sb = {};
        sa = MFMA32(kf[0][0], aq[qf][0], sa);
        sa = MFMA32(kf[0][1], aq[qf][1], sa);
        sb = MFMA32(kf[1][0], aq[qf][0], sb);
        sb = MFMA32(kf[1][1], aq[qf][1], sb);
        uint4 pu;
        pu.x = cvtpk(fexp2(sa[0]), fexp2(sa[1]));
        pu.y = cvtpk(fexp2(sa[2]), fexp2(sa[3]));
        pu.z = cvtpk(fexp2(sb[0]), fexp2(sb[1]));
        pu.w = cvtpk(fexp2(sb[2]), fexp2(sb[3]));
        short8 pb = __builtin_bit_cast(short8, pu);
        lacc[qf] = MFMA32(ones8, pb, lacc[qf]);
#pragma unroll
        for (int nt = 0; nt < 4; ++nt)
          oacc[qf][nt] = MFMA32(vf[nt], pb, oacc[qf][nt]);
      }
    }
  }

  const int b = bh >> 4, h = bh & 15;
  // lacc: ones*P rows all equal the P column-sum; col = r16 = this lane's q
  // in the epilogue mapping below -> no cross-lane reduction needed.
  float linv[4];
#pragma unroll
  for (int qf = 0; qf < 4; ++qf) linv[qf] = 1.0f / lacc[qf][0];
#pragma unroll
  for (int qf = 0; qf < 4; ++qf) {
    int q = qbase + qf * 16 + r16;
    size_t rowb = ((size_t)(b * Lq + q)) * Dm + h * HD;
#pragma unroll
    for (int nt = 0; nt < 4; ++nt) {
      f32x4 o = oacc[qf][nt];
      uint2 pkd;
      pkd.x = pk2(o[0] * linv[qf], o[1] * linv[qf]);
      pkd.y = pk2(o[2] * linv[qf], o[3] * linv[qf]);
      *(uint2*)&Oa[rowb + nt * 16 + quad * 4] = pkd;
    }
  }
}

// ---------------- launcher ----------------
extern "C" void kernel_launch(void* const* d_in, const int* in_sizes, int n_in,
                              void* d_out, int out_size, void* d_ws, size_t ws_size,
                              hipStream_t stream) {
  const float* q  = (const float*)d_in[0];
  const float* k  = (const float*)d_in[1];
  const float* v  = (const float*)d_in[2];
  const float* Wq = (const float*)d_in[3];
  const float* bq = (const float*)d_in[4];
  const float* Wk = (const float*)d_in[5];
  const float* bk = (const float*)d_in[6];
  const float* Wv = (const float*)d_in[7];
  const float* bv = (const float*)d_in[8];
  const float* Wo = (const float*)d_in[9];
  const float* bo = (const float*)d_in[10];

  const int NA = Bsz * Lq * Dm;  // 8388608
  u16* abuf = (u16*)d_ws;            // [3][M][K] activations bf16; later Oa
  u16* Qh   = abuf + (size_t)3 * NA;
  u16* Kh   = Qh   + NA;
  u16* Vtg  = Kh   + NA;
  u16* wqb  = Vtg  + NA;
  u16* wkb  = wqb  + 1048576;
  u16* wvb  = wkb  + 1048576;
  u16* wob  = wvb  + 1048576;

  castw<<<dim3(512, 4), 256, 0, stream>>>(Wq, Wk, Wv, Wo, wqb, wkb, wvb, wob);
  castk3<<<dim3(NA / 2048, 3), 256, 0, stream>>>(q, k, v, abuf);

  qkv_gemm<<<dim3(8, 64, 3), 256, 0, stream>>>(abuf, wqb, wkb, wvb, bq, bk, bv, Qh, Kh, Vtg);

  attn4<<<dim3(Lq / 256, Bsz * NH), 256, 0, stream>>>(Qh, Kh, Vtg, abuf);

  gemm_wo<<<dim3(16, 64), 256, 0, stream>>>(abuf, wob, bo, (float*)d_out);
}